// Round 5
// baseline (2325.917 us; speedup 1.0000x reference)
//
#include <hip/hip_runtime.h>

typedef _Float16 f16;
typedef _Float16 f16x2 __attribute__((ext_vector_type(2)));
typedef _Float16 f16x8 __attribute__((ext_vector_type(8)));
typedef float f32x4 __attribute__((ext_vector_type(4)));
typedef unsigned int u32;
typedef unsigned short u16;

#define B_SZ 64
#define T_SZ 512
#define DIN 768
#define H_SZ 256
#define TH 768               // 3*H
#define M_ROWS (B_SZ * T_SZ) // 32768

// Workspace layout (bytes). Total = 69,861,376 B (~66.6 MB).
#define O_WT1 ((size_t)0)
#define O_WT2 (O_WT1 + (size_t)768 * 768 * 2)
#define O_H1 (O_WT2 + (size_t)768 * 1024 * 2)
#define O_G (O_H1 + (size_t)M_ROWS * H_SZ * 2)

__device__ __forceinline__ u32 pk2(float a, float b) {
  union { f16 h[2]; u32 u; } x;
  x.h[0] = (f16)a;
  x.h[1] = (f16)b;
  return x.u;
}

__device__ __forceinline__ float dot2f(u32 w, u32 h, float acc) {
#if __has_builtin(__builtin_amdgcn_fdot2)
  union { u32 u; f16x2 v; } a, b;
  a.u = w;
  b.u = h;
  return __builtin_amdgcn_fdot2(a.v, b.v, acc, false);
#else
  union { u32 u; f16 h[2]; } a, b;
  a.u = w;
  b.u = h;
  acc = fmaf((float)a.h[0], (float)b.h[0], acc);
  acc = fmaf((float)a.h[1], (float)b.h[1], acc);
  return acc;
#endif
}

__device__ __forceinline__ float sigmf_(float x) {
  return 1.0f / (1.0f + __expf(-x));
}
__device__ __forceinline__ float tanhf_(float x) {
  float e = __expf(-2.0f * fabsf(x));
  float r = (1.0f - e) / (1.0f + e);
  return copysignf(r, x);
}

// ---------------------------------------------------------------------------
// Transpose+convert: W [K][N] fp32 -> Wt [N][K] fp16
// ---------------------------------------------------------------------------
__global__ __launch_bounds__(256) void k_transpose(const float* __restrict__ W,
                                                   f16* __restrict__ Wt, int K,
                                                   int N) {
  __shared__ f16 tile[32][33];
  int tx = threadIdx.x, ty = threadIdx.y;
  int n0 = blockIdx.x * 32, k0 = blockIdx.y * 32;
#pragma unroll
  for (int q = 0; q < 4; ++q) {
    int k = k0 + ty + q * 8;
    tile[ty + q * 8][tx] = (f16)W[(size_t)k * N + n0 + tx];
  }
  __syncthreads();
#pragma unroll
  for (int q = 0; q < 4; ++q) {
    int n = n0 + ty + q * 8;
    Wt[(size_t)n * K + k0 + tx] = tile[tx][ty + q * 8];
  }
}

// ---------------------------------------------------------------------------
// fp16 MFMA GEMM: C[M][768] = A @ Bt^T + bias.
// A: rows from A32 (fp32, k<768, converted on stage) and/or AH (fp16, k>=768).
// Bt: [768 n][K k] fp16 (pre-transposed weights). Tile 128x128, BK=32.
// ---------------------------------------------------------------------------
#define LDK 40 // padded LDS k-stride (halves); 80 B rows -> 2-way banks (free)
__global__ __launch_bounds__(256, 2) void k_gemm(
    const float* __restrict__ A32, const f16* __restrict__ AH,
    const f16* __restrict__ Bt, const float* __restrict__ bias,
    f16* __restrict__ C, int K, int bstride) {
  __shared__ __align__(16) f16 Asm[128 * LDK];
  __shared__ __align__(16) f16 Bsm[128 * LDK];
  int tid = threadIdx.x;
  int lane = tid & 63, wave = tid >> 6;
  int wm = wave & 1, wn = wave >> 1;
  int fm = lane & 15, fk = (lane >> 4) * 8;
  int srow = tid >> 1, skp = (tid & 1) * 16;
  size_t r0 = (size_t)blockIdx.y * 128;
  int n0 = blockIdx.x * 128;
  f32x4 acc[4][4] = {};

  for (int k0 = 0; k0 < K; k0 += 32) {
    __syncthreads();
    // Stage A-tile (128 x 32 halves): 2 threads/row, 16 halves each.
    if (k0 < DIN) {
      const float* src = A32 + (r0 + srow) * DIN + k0 + skp;
      float4 v0 = *(const float4*)(src);
      float4 v1 = *(const float4*)(src + 4);
      float4 v2 = *(const float4*)(src + 8);
      float4 v3 = *(const float4*)(src + 12);
      uint4 w0 = make_uint4(pk2(v0.x, v0.y), pk2(v0.z, v0.w), pk2(v1.x, v1.y),
                            pk2(v1.z, v1.w));
      uint4 w1 = make_uint4(pk2(v2.x, v2.y), pk2(v2.z, v2.w), pk2(v3.x, v3.y),
                            pk2(v3.z, v3.w));
      *(uint4*)&Asm[srow * LDK + skp] = w0;
      *(uint4*)&Asm[srow * LDK + skp + 8] = w1;
    } else {
      const uint4* src =
          (const uint4*)(AH + (r0 + srow) * H_SZ + (k0 - DIN) + skp);
      *(uint4*)&Asm[srow * LDK + skp] = src[0];
      *(uint4*)&Asm[srow * LDK + skp + 8] = src[1];
    }
    // Stage B-tile (128 n x 32 k halves) from pre-transposed fp16 weights.
    const uint4* bsrc =
        (const uint4*)(Bt + (size_t)(n0 + srow) * bstride + k0 + skp);
    *(uint4*)&Bsm[srow * LDK + skp] = bsrc[0];
    *(uint4*)&Bsm[srow * LDK + skp + 8] = bsrc[1];
    __syncthreads();

    f16x8 af[4], bf[4];
#pragma unroll
    for (int mt = 0; mt < 4; ++mt)
      af[mt] = *(const f16x8*)&Asm[(wm * 64 + mt * 16 + fm) * LDK + fk];
#pragma unroll
    for (int nt = 0; nt < 4; ++nt)
      bf[nt] = *(const f16x8*)&Bsm[(wn * 64 + nt * 16 + fm) * LDK + fk];
#pragma unroll
    for (int mt = 0; mt < 4; ++mt)
#pragma unroll
      for (int nt = 0; nt < 4; ++nt)
        acc[mt][nt] = __builtin_amdgcn_mfma_f32_16x16x32_f16(af[mt], bf[nt],
                                                             acc[mt][nt], 0, 0, 0);
  }

  // Epilogue: C/D layout col=lane&15, row=(lane>>4)*4+reg (dtype-independent).
  int ccol = lane & 15, crb = (lane >> 4) * 4;
#pragma unroll
  for (int nt = 0; nt < 4; ++nt) {
    int col = n0 + wn * 64 + nt * 16 + ccol;
    float bv = bias[col];
#pragma unroll
    for (int mt = 0; mt < 4; ++mt) {
      size_t rb = r0 + wm * 64 + mt * 16 + crb;
#pragma unroll
      for (int rg = 0; rg < 4; ++rg)
        C[(rb + rg) * TH + col] = (f16)(acc[mt][nt][rg] + bv);
    }
  }
}

// ---------------------------------------------------------------------------
// Recurrence: one workgroup (1024 thr) per batch row, 4-way k-split.
// Thread (cg, kq): cols {cg, cg+256, cg+512}, k-quarter [kq*64, kq*64+64).
// Per-thread weights: w2[3][32] = 96 packed fp16-pair registers.
//
// History: the 512-thread / 192-reg variant sat at 595 us with VGPR_Count
// pinned to 128 across launch_bounds(512,2)/(512,1)/waves_per_eu(2,2)+90KB
// LDS -- the allocator kept the 192-entry array out of arch VGPRs no matter
// the budget (AGPR/scratch), costing ~1000+ cyc/step of copy traffic. 96
// regs fits INSIDE the 128 budget, making the question moot. Total dot work
// per CU is unchanged (4 waves x 96 dot2 per SIMD per step).
// LDS kept > 80 KB so a second 1024-thread block can never co-reside (that
// would halve the VGPR budget to 64). Grid = 64 blocks on 256 CUs anyway.
// ---------------------------------------------------------------------------
template <int CH>
__device__ __forceinline__ void load_chunk(const float* __restrict__ Whh,
                                           f16* __restrict__ s_stage,
                                           u32 (&w2)[3][32], int tid, int cg,
                                           int kq) {
  __syncthreads();
  // Stage rows [CH*32, CH*32+32) of Whh (fp32 [256][768]) into LDS as fp16.
#pragma unroll
  for (int q = 0; q < 6; ++q) {
    int idx4 = tid + q * 1024; // 6144 float4 = 32*768 floats
    float4 v = *(const float4*)(Whh + (size_t)CH * 32 * TH + (size_t)idx4 * 4);
    union { f16 h[4]; uint2 u; } pw;
    pw.h[0] = (f16)v.x;
    pw.h[1] = (f16)v.y;
    pw.h[2] = (f16)v.z;
    pw.h[3] = (f16)v.w;
    *(uint2*)&s_stage[idx4 * 4] = pw.u;
  }
  __syncthreads();
  if ((CH >> 1) == kq) { // this chunk belongs to my k-quarter (uniform branch)
    constexpr int ib = (CH & 1) * 16;
#pragma unroll
    for (int i2 = 0; i2 < 16; ++i2) {
#pragma unroll
      for (int c = 0; c < 3; ++c) {
        int col = cg + c * 256;
        w2[c][ib + i2] = pk2((float)s_stage[(2 * i2) * TH + col],
                             (float)s_stage[(2 * i2 + 1) * TH + col]);
      }
    }
  }
}

__global__ __launch_bounds__(1024, 1) void k_rec(
    const f16* __restrict__ G, const float* __restrict__ Whh,
    const float* __restrict__ bhh, const float* __restrict__ tau,
    float* __restrict__ out, int out_off, f16* __restrict__ H1out) {
  __shared__ __align__(16) u16 s_h16[256];
  __shared__ float s_h32[256];
  __shared__ float s_part[3 * 768]; // [kq-1][c][cg] partials from quarters 1-3
  // 56*TH halves = 84 KB (only first 32*TH used for staging): total LDS
  // ~94.6 KB > 80 KB forces 1 block/CU -> 4 waves/EU target -> 128-VGPR
  // budget, which the 96-reg w2 fits inside.
  __shared__ __align__(16) f16 s_stage[56 * TH];

  int tid = threadIdx.x;
  int b = blockIdx.x;
  int cg = tid & 255;
  int kq = tid >> 8; // 0..3 (wave-uniform)

  // --- Load W_hh into registers: 3 cols x 32 packed pairs = 96 VGPRs ---
  u32 w2[3][32];
  load_chunk<0>(Whh, s_stage, w2, tid, cg, kq);
  load_chunk<1>(Whh, s_stage, w2, tid, cg, kq);
  load_chunk<2>(Whh, s_stage, w2, tid, cg, kq);
  load_chunk<3>(Whh, s_stage, w2, tid, cg, kq);
  load_chunk<4>(Whh, s_stage, w2, tid, cg, kq);
  load_chunk<5>(Whh, s_stage, w2, tid, cg, kq);
  load_chunk<6>(Whh, s_stage, w2, tid, cg, kq);
  load_chunk<7>(Whh, s_stage, w2, tid, cg, kq);

  float bb0 = bhh[cg], bb1 = bhh[cg + 256], bb2 = bhh[cg + 512];
  float invt = 1.0f / tau[0];
  float om = 1.0f - invt;
  if (tid < 256) {
    s_h16[tid] = 0;
    s_h32[tid] = 0.0f;
  }
  __syncthreads();

  const f16* gbase = G + (size_t)b * T_SZ * TH;
  float* obase = out + (size_t)b * T_SZ * 512 + out_off;
  f16* hbase = H1out ? H1out + (size_t)b * T_SZ * H_SZ : (f16*)0;
  // My quarter's h pairs: halves [64*kq, 64*kq+64) = uint4 [8*kq, 8*kq+8).
  const uint4* hv4 = (const uint4*)s_h16 + kq * 8;

  for (int t = 0; t < T_SZ; ++t) {
    // Prefetch gi for this step (independent of h -> overlaps the dot loop).
    f16 gg0 = (f16)0.f, gg1 = (f16)0.f, gg2 = (f16)0.f;
    if (tid < 256) {
      const f16* gp = gbase + (size_t)t * TH + cg;
      gg0 = gp[0];
      gg1 = gp[256];
      gg2 = gp[512];
    }
    // gh partial dots over my k-quarter (h pairs broadcast from LDS).
    float a0 = 0.f, a1 = 0.f, a2 = 0.f;
#pragma unroll
    for (int ii = 0; ii < 8; ++ii) {
      uint4 hv = hv4[ii];
      a0 = dot2f(w2[0][ii * 4 + 0], hv.x, a0);
      a1 = dot2f(w2[1][ii * 4 + 0], hv.x, a1);
      a2 = dot2f(w2[2][ii * 4 + 0], hv.x, a2);
      a0 = dot2f(w2[0][ii * 4 + 1], hv.y, a0);
      a1 = dot2f(w2[1][ii * 4 + 1], hv.y, a1);
      a2 = dot2f(w2[2][ii * 4 + 1], hv.y, a2);
      a0 = dot2f(w2[0][ii * 4 + 2], hv.z, a0);
      a1 = dot2f(w2[1][ii * 4 + 2], hv.z, a1);
      a2 = dot2f(w2[2][ii * 4 + 2], hv.z, a2);
      a0 = dot2f(w2[0][ii * 4 + 3], hv.w, a0);
      a1 = dot2f(w2[1][ii * 4 + 3], hv.w, a1);
      a2 = dot2f(w2[2][ii * 4 + 3], hv.w, a2);
    }
    if (kq) {
      int pb = (kq - 1) * 768 + cg;
      s_part[pb] = a0;
      s_part[pb + 256] = a1;
      s_part[pb + 512] = a2;
    }
    __syncthreads();
    if (tid < 256) {
      float ghr = a0 + s_part[cg] + s_part[768 + cg] + s_part[1536 + cg] + bb0;
      float ghz = a1 + s_part[256 + cg] + s_part[1024 + cg] +
                  s_part[1792 + cg] + bb1;
      float ghn = a2 + s_part[512 + cg] + s_part[1280 + cg] +
                  s_part[2048 + cg] + bb2;
      float r = sigmf_((float)gg0 + ghr);
      float z = sigmf_((float)gg1 + ghz);
      float n = tanhf_((float)gg2 + r * ghn);
      float hold = s_h32[cg];
      float hc = (1.0f - z) * n + z * hold;
      float hn2 = om * hold + invt * hc;
      s_h32[cg] = hn2;
      union { f16 h; u16 s; } hb;
      hb.h = (f16)hn2;
      s_h16[cg] = hb.s;
      obase[(size_t)t * 512 + cg] = hn2;
      if (hbase) hbase[(size_t)t * H_SZ + cg] = (f16)hn2;
    }
    __syncthreads();
  }
}

// ---------------------------------------------------------------------------
extern "C" void kernel_launch(void* const* d_in, const int* in_sizes, int n_in,
                              void* d_out, int out_size, void* d_ws,
                              size_t ws_size, hipStream_t stream) {
  const float* enc = (const float*)d_in[0];
  const float* tau1 = (const float*)d_in[1];
  const float* tau2 = (const float*)d_in[2];
  const float* Wih1 = (const float*)d_in[3];
  const float* Whh1 = (const float*)d_in[4];
  const float* bih1 = (const float*)d_in[5];
  const float* bhh1 = (const float*)d_in[6];
  const float* Wih2 = (const float*)d_in[7];
  const float* Whh2 = (const float*)d_in[8];
  const float* bih2 = (const float*)d_in[9];
  const float* bhh2 = (const float*)d_in[10];
  float* out = (float*)d_out;
  char* ws = (char*)d_ws;

  f16* Wt1 = (f16*)(ws + O_WT1); // [768 n][768 k]
  f16* Wt2 = (f16*)(ws + O_WT2); // [768 n][1024 k]
  f16* H1 = (f16*)(ws + O_H1);   // [32768][256] h1 seq, fp16
  f16* G = (f16*)(ws + O_G);     // [32768][768] gi buffer (reused layer1/2)

  // Weight transposes (fp32 [k][n] -> fp16 [n][k]).
  k_transpose<<<dim3(24, 24), dim3(32, 8), 0, stream>>>(Wih1, Wt1, 768, 768);
  k_transpose<<<dim3(24, 32), dim3(32, 8), 0, stream>>>(Wih2, Wt2, 1024, 768);

  // Layer 1: gi1 = X @ W_ih1 + b_ih1, then recurrence.
  k_gemm<<<dim3(6, 256), 256, 0, stream>>>(enc, (const f16*)0, Wt1, bih1, G,
                                           768, 768);
  k_rec<<<64, 1024, 0, stream>>>(G, Whh1, bhh1, tau1, out, 0, H1);

  // Layer 2: gi2 = [X | H1] @ W_ih2 + b_ih2, then recurrence.
  k_gemm<<<dim3(6, 256), 256, 0, stream>>>(enc, H1, Wt2, bih2, G, 1024, 1024);
  k_rec<<<64, 1024, 0, stream>>>(G, Whh2, bhh2, tau2, out, 256, (f16*)0);
}

// Round 6
// 1897.771 us; speedup vs baseline: 1.2256x; 1.2256x over previous
//
#include <hip/hip_runtime.h>

typedef _Float16 f16;
typedef _Float16 f16x2 __attribute__((ext_vector_type(2)));
typedef _Float16 f16x8 __attribute__((ext_vector_type(8)));
typedef float f32x4 __attribute__((ext_vector_type(4)));
typedef unsigned int u32;
typedef unsigned short u16;

#define B_SZ 64
#define T_SZ 512
#define DIN 768
#define H_SZ 256
#define TH 768               // 3*H
#define M_ROWS (B_SZ * T_SZ) // 32768

// Workspace layout (bytes). Total = 69,861,376 B (~66.6 MB).
#define O_WT1 ((size_t)0)
#define O_WT2 (O_WT1 + (size_t)768 * 768 * 2)
#define O_H1 (O_WT2 + (size_t)768 * 1024 * 2)
#define O_G (O_H1 + (size_t)M_ROWS * H_SZ * 2)

__device__ __forceinline__ u32 pk2(float a, float b) {
  union { f16 h[2]; u32 u; } x;
  x.h[0] = (f16)a;
  x.h[1] = (f16)b;
  return x.u;
}

__device__ __forceinline__ float dot2f(u32 w, u32 h, float acc) {
#if __has_builtin(__builtin_amdgcn_fdot2)
  union { u32 u; f16x2 v; } a, b;
  a.u = w;
  b.u = h;
  return __builtin_amdgcn_fdot2(a.v, b.v, acc, false);
#else
  union { u32 u; f16 h[2]; } a, b;
  a.u = w;
  b.u = h;
  acc = fmaf((float)a.h[0], (float)b.h[0], acc);
  acc = fmaf((float)a.h[1], (float)b.h[1], acc);
  return acc;
#endif
}

__device__ __forceinline__ float sigmf_(float x) {
  return 1.0f / (1.0f + __expf(-x));
}
__device__ __forceinline__ float tanhf_(float x) {
  float e = __expf(-2.0f * fabsf(x));
  float r = (1.0f - e) / (1.0f + e);
  return copysignf(r, x);
}

// ---------------------------------------------------------------------------
// Transpose+convert: W [K][N] fp32 -> Wt [N][K] fp16
// ---------------------------------------------------------------------------
__global__ __launch_bounds__(256) void k_transpose(const float* __restrict__ W,
                                                   f16* __restrict__ Wt, int K,
                                                   int N) {
  __shared__ f16 tile[32][33];
  int tx = threadIdx.x, ty = threadIdx.y;
  int n0 = blockIdx.x * 32, k0 = blockIdx.y * 32;
#pragma unroll
  for (int q = 0; q < 4; ++q) {
    int k = k0 + ty + q * 8;
    tile[ty + q * 8][tx] = (f16)W[(size_t)k * N + n0 + tx];
  }
  __syncthreads();
#pragma unroll
  for (int q = 0; q < 4; ++q) {
    int n = n0 + ty + q * 8;
    Wt[(size_t)n * K + k0 + tx] = tile[tx][ty + q * 8];
  }
}

// ---------------------------------------------------------------------------
// fp16 MFMA GEMM: C[M][768] = A @ Bt^T + bias.
// A: rows from A32 (fp32, k<768, converted on stage) and/or AH (fp16, k>=768).
// Bt: [768 n][K k] fp16 (pre-transposed weights). Tile 128x128, BK=32.
// ---------------------------------------------------------------------------
#define LDK 40 // padded LDS k-stride (halves); 80 B rows -> 2-way banks (free)
__global__ __launch_bounds__(256, 2) void k_gemm(
    const float* __restrict__ A32, const f16* __restrict__ AH,
    const f16* __restrict__ Bt, const float* __restrict__ bias,
    f16* __restrict__ C, int K, int bstride) {
  __shared__ __align__(16) f16 Asm[128 * LDK];
  __shared__ __align__(16) f16 Bsm[128 * LDK];
  int tid = threadIdx.x;
  int lane = tid & 63, wave = tid >> 6;
  int wm = wave & 1, wn = wave >> 1;
  int fm = lane & 15, fk = (lane >> 4) * 8;
  int srow = tid >> 1, skp = (tid & 1) * 16;
  size_t r0 = (size_t)blockIdx.y * 128;
  int n0 = blockIdx.x * 128;
  f32x4 acc[4][4] = {};

  for (int k0 = 0; k0 < K; k0 += 32) {
    __syncthreads();
    // Stage A-tile (128 x 32 halves): 2 threads/row, 16 halves each.
    if (k0 < DIN) {
      const float* src = A32 + (r0 + srow) * DIN + k0 + skp;
      float4 v0 = *(const float4*)(src);
      float4 v1 = *(const float4*)(src + 4);
      float4 v2 = *(const float4*)(src + 8);
      float4 v3 = *(const float4*)(src + 12);
      uint4 w0 = make_uint4(pk2(v0.x, v0.y), pk2(v0.z, v0.w), pk2(v1.x, v1.y),
                            pk2(v1.z, v1.w));
      uint4 w1 = make_uint4(pk2(v2.x, v2.y), pk2(v2.z, v2.w), pk2(v3.x, v3.y),
                            pk2(v3.z, v3.w));
      *(uint4*)&Asm[srow * LDK + skp] = w0;
      *(uint4*)&Asm[srow * LDK + skp + 8] = w1;
    } else {
      const uint4* src =
          (const uint4*)(AH + (r0 + srow) * H_SZ + (k0 - DIN) + skp);
      *(uint4*)&Asm[srow * LDK + skp] = src[0];
      *(uint4*)&Asm[srow * LDK + skp + 8] = src[1];
    }
    // Stage B-tile (128 n x 32 k halves) from pre-transposed fp16 weights.
    const uint4* bsrc =
        (const uint4*)(Bt + (size_t)(n0 + srow) * bstride + k0 + skp);
    *(uint4*)&Bsm[srow * LDK + skp] = bsrc[0];
    *(uint4*)&Bsm[srow * LDK + skp + 8] = bsrc[1];
    __syncthreads();

    f16x8 af[4], bf[4];
#pragma unroll
    for (int mt = 0; mt < 4; ++mt)
      af[mt] = *(const f16x8*)&Asm[(wm * 64 + mt * 16 + fm) * LDK + fk];
#pragma unroll
    for (int nt = 0; nt < 4; ++nt)
      bf[nt] = *(const f16x8*)&Bsm[(wn * 64 + nt * 16 + fm) * LDK + fk];
#pragma unroll
    for (int mt = 0; mt < 4; ++mt)
#pragma unroll
      for (int nt = 0; nt < 4; ++nt)
        acc[mt][nt] = __builtin_amdgcn_mfma_f32_16x16x32_f16(af[mt], bf[nt],
                                                             acc[mt][nt], 0, 0, 0);
  }

  // Epilogue: C/D layout col=lane&15, row=(lane>>4)*4+reg (dtype-independent).
  int ccol = lane & 15, crb = (lane >> 4) * 4;
#pragma unroll
  for (int nt = 0; nt < 4; ++nt) {
    int col = n0 + wn * 64 + nt * 16 + ccol;
    float bv = bias[col];
#pragma unroll
    for (int mt = 0; mt < 4; ++mt) {
      size_t rb = r0 + wm * 64 + mt * 16 + crb;
#pragma unroll
      for (int rg = 0; rg < 4; ++rg)
        C[(rb + rg) * TH + col] = (f16)(acc[mt][nt][rg] + bv);
    }
  }
}

// ---------------------------------------------------------------------------
// Recurrence v3: one workgroup (768 thr) per batch row. Thread c owns gate
// column c (c<256: r, c<512: z, else n) over the FULL k=256 -- no k-split,
// no k-reduction. Weights are 128 INDIVIDUALLY NAMED u32 scalars (packed
// fp16 pairs): no array -> no alloca -> PromoteAlloca/SROA can't refuse ->
// guaranteed arch VGPRs. (All array-based variants pinned VGPR_Count at an
// occupancy boundary with the array in scratch/AGPR spill: the alloca was
// too big to promote, so every step re-read the weights. That was the 595us.)
// h state broadcast from LDS as 32 uint4 (same-address = conflict-free).
// Cross-gate handoff via 3 small LDS arrays; two barriers per step.
// __launch_bounds__(768,3): 12 waves = 1 block/CU, VGPR cap ~170 (>128+temps).
// LDS kept >80 KB so a second block can never co-reside.
// ---------------------------------------------------------------------------
#define DECLW(c)                                                               \
  u32 w##c##_0, w##c##_1, w##c##_2, w##c##_3, w##c##_4, w##c##_5, w##c##_6,    \
      w##c##_7, w##c##_8, w##c##_9, w##c##_10, w##c##_11, w##c##_12,           \
      w##c##_13, w##c##_14, w##c##_15

// Stage rows [CH*32, CH*32+32) of Whh (fp32 [256][768]) into LDS as fp16,
// then pull this thread's column: 16 packed pairs -> named scalars.
#define STAGE_CHUNK(CH)                                                        \
  __syncthreads();                                                             \
  _Pragma("unroll") for (int q = 0; q < 8; ++q) {                              \
    int idx4 = tid + q * 768;                                                  \
    float4 v = *(const float4*)(Whh + (size_t)(CH)*32 * TH + (size_t)idx4 * 4);\
    union { f16 h[4]; uint2 u; } pw;                                           \
    pw.h[0] = (f16)v.x;                                                        \
    pw.h[1] = (f16)v.y;                                                        \
    pw.h[2] = (f16)v.z;                                                        \
    pw.h[3] = (f16)v.w;                                                        \
    *(uint2*)&s_stage[idx4 * 4] = pw.u;                                        \
  }                                                                            \
  __syncthreads();

#define PKW(CH, I, R0, R1)                                                     \
  w##CH##_##I =                                                                \
      pk2((float)s_stage[(R0)*TH + tid], (float)s_stage[(R1)*TH + tid])

#define LOADW(CH)                                                              \
  STAGE_CHUNK(CH)                                                              \
  PKW(CH, 0, 0, 1);                                                            \
  PKW(CH, 1, 2, 3);                                                            \
  PKW(CH, 2, 4, 5);                                                            \
  PKW(CH, 3, 6, 7);                                                            \
  PKW(CH, 4, 8, 9);                                                            \
  PKW(CH, 5, 10, 11);                                                          \
  PKW(CH, 6, 12, 13);                                                          \
  PKW(CH, 7, 14, 15);                                                          \
  PKW(CH, 8, 16, 17);                                                          \
  PKW(CH, 9, 18, 19);                                                          \
  PKW(CH, 10, 20, 21);                                                         \
  PKW(CH, 11, 22, 23);                                                         \
  PKW(CH, 12, 24, 25);                                                         \
  PKW(CH, 13, 26, 27);                                                         \
  PKW(CH, 14, 28, 29);                                                         \
  PKW(CH, 15, 30, 31)

// One k-chunk of 32 (16 pairs) of the dot product, h pairs from LDS uint4s.
#define DOTCH(CH, ACC)                                                         \
  {                                                                            \
    uint4 hv = hvp[4 * (CH) + 0];                                              \
    ACC = dot2f(w##CH##_0, hv.x, ACC);                                         \
    ACC = dot2f(w##CH##_1, hv.y, ACC);                                         \
    ACC = dot2f(w##CH##_2, hv.z, ACC);                                         \
    ACC = dot2f(w##CH##_3, hv.w, ACC);                                         \
    hv = hvp[4 * (CH) + 1];                                                    \
    ACC = dot2f(w##CH##_4, hv.x, ACC);                                         \
    ACC = dot2f(w##CH##_5, hv.y, ACC);                                         \
    ACC = dot2f(w##CH##_6, hv.z, ACC);                                         \
    ACC = dot2f(w##CH##_7, hv.w, ACC);                                         \
    hv = hvp[4 * (CH) + 2];                                                    \
    ACC = dot2f(w##CH##_8, hv.x, ACC);                                         \
    ACC = dot2f(w##CH##_9, hv.y, ACC);                                         \
    ACC = dot2f(w##CH##_10, hv.z, ACC);                                        \
    ACC = dot2f(w##CH##_11, hv.w, ACC);                                        \
    hv = hvp[4 * (CH) + 3];                                                    \
    ACC = dot2f(w##CH##_12, hv.x, ACC);                                        \
    ACC = dot2f(w##CH##_13, hv.y, ACC);                                        \
    ACC = dot2f(w##CH##_14, hv.z, ACC);                                        \
    ACC = dot2f(w##CH##_15, hv.w, ACC);                                        \
  }

__global__ __launch_bounds__(768, 3) void k_rec(
    const f16* __restrict__ G, const float* __restrict__ Whh,
    const float* __restrict__ bhh, const float* __restrict__ tau,
    float* __restrict__ out, int out_off, f16* __restrict__ H1out) {
  __shared__ __align__(16) u16 s_h16[256]; // h state, packed fp16
  __shared__ float s_h32[256];             // h state, fp32
  __shared__ float s_pz[256];              // z-gate handoff (gi+gh+biases)
  __shared__ float s_pnh[256];             // n-gate gh part (+bhh)
  __shared__ float s_pni[256];             // n-gate gi part
  // 56*TH halves = 84 KB (only first 32*TH used for staging): total LDS
  // ~90 KB > 80 KB forces 1 block/CU.
  __shared__ __align__(16) f16 s_stage[56 * TH];

  int tid = threadIdx.x; // == my gate column c in [0, 768)
  int b = blockIdx.x;

  // --- Weights: 128 named u32 scalars (256 k-halves packed in pairs) ---
  DECLW(0);
  DECLW(1);
  DECLW(2);
  DECLW(3);
  DECLW(4);
  DECLW(5);
  DECLW(6);
  DECLW(7);
  LOADW(0);
  LOADW(1);
  LOADW(2);
  LOADW(3);
  LOADW(4);
  LOADW(5);
  LOADW(6);
  LOADW(7);

  float bb = bhh[tid];
  float invt = 1.0f / tau[0];
  float om = 1.0f - invt;
  if (tid < 256) {
    s_h16[tid] = 0;
    s_h32[tid] = 0.0f;
  }
  __syncthreads();

  const f16* gbase = G + (size_t)b * T_SZ * TH;
  float* obase = out + (size_t)b * T_SZ * 512 + out_off;
  f16* hbase = H1out ? H1out + (size_t)b * T_SZ * H_SZ : (f16*)0;
  const uint4* hvp = (const uint4*)s_h16;

  for (int t = 0; t < T_SZ; ++t) {
    // gi for my column (issued early; consumed after the dot loop).
    float gg = (float)gbase[(size_t)t * TH + tid];
    // Full-k dot: 128 packed-pair dot2s, two independent chains.
    float aA = 0.f, aB = 0.f;
    DOTCH(0, aA);
    DOTCH(1, aB);
    DOTCH(2, aA);
    DOTCH(3, aB);
    DOTCH(4, aA);
    DOTCH(5, aB);
    DOTCH(6, aA);
    DOTCH(7, aB);
    float a = aA + aB + bb; // gh (incl. b_hh) for my column
    // Cross-gate handoff (each branch is wave-uniform: 4 waves per gate).
    if (tid >= 512) {
      s_pnh[tid - 512] = a;  // gh_n (+bhh)
      s_pni[tid - 512] = gg; // gi_n
    } else if (tid >= 256) {
      s_pz[tid - 256] = a + gg; // full z-gate preactivation
    }
    __syncthreads();
    if (tid < 256) {
      float r = sigmf_(a + gg);
      float z = sigmf_(s_pz[tid]);
      float n = tanhf_(s_pni[tid] + r * s_pnh[tid]);
      float hold = s_h32[tid];
      float hc = (1.0f - z) * n + z * hold;
      float hn2 = om * hold + invt * hc;
      s_h32[tid] = hn2;
      union { f16 h; u16 s; } hb;
      hb.h = (f16)hn2;
      s_h16[tid] = hb.s;
      obase[(size_t)t * 512 + tid] = hn2;
      if (hbase) hbase[(size_t)t * H_SZ + tid] = (f16)hn2;
    }
    __syncthreads();
  }
}

// ---------------------------------------------------------------------------
extern "C" void kernel_launch(void* const* d_in, const int* in_sizes, int n_in,
                              void* d_out, int out_size, void* d_ws,
                              size_t ws_size, hipStream_t stream) {
  const float* enc = (const float*)d_in[0];
  const float* tau1 = (const float*)d_in[1];
  const float* tau2 = (const float*)d_in[2];
  const float* Wih1 = (const float*)d_in[3];
  const float* Whh1 = (const float*)d_in[4];
  const float* bih1 = (const float*)d_in[5];
  const float* bhh1 = (const float*)d_in[6];
  const float* Wih2 = (const float*)d_in[7];
  const float* Whh2 = (const float*)d_in[8];
  const float* bih2 = (const float*)d_in[9];
  const float* bhh2 = (const float*)d_in[10];
  float* out = (float*)d_out;
  char* ws = (char*)d_ws;

  f16* Wt1 = (f16*)(ws + O_WT1); // [768 n][768 k]
  f16* Wt2 = (f16*)(ws + O_WT2); // [768 n][1024 k]
  f16* H1 = (f16*)(ws + O_H1);   // [32768][256] h1 seq, fp16
  f16* G = (f16*)(ws + O_G);     // [32768][768] gi buffer (reused layer1/2)

  // Weight transposes (fp32 [k][n] -> fp16 [n][k]).
  k_transpose<<<dim3(24, 24), dim3(32, 8), 0, stream>>>(Wih1, Wt1, 768, 768);
  k_transpose<<<dim3(24, 32), dim3(32, 8), 0, stream>>>(Wih2, Wt2, 1024, 768);

  // Layer 1: gi1 = X @ W_ih1 + b_ih1, then recurrence.
  k_gemm<<<dim3(6, 256), 256, 0, stream>>>(enc, (const f16*)0, Wt1, bih1, G,
                                           768, 768);
  k_rec<<<64, 768, 0, stream>>>(G, Whh1, bhh1, tau1, out, 0, H1);

  // Layer 2: gi2 = [X | H1] @ W_ih2 + b_ih2, then recurrence.
  k_gemm<<<dim3(6, 256), 256, 0, stream>>>(enc, H1, Wt2, bih2, G, 1024, 1024);
  k_rec<<<64, 768, 0, stream>>>(G, Whh2, bhh2, tau2, out, 256, (f16*)0);
}